// Round 13
// baseline (680.881 us; speedup 1.0000x reference)
//
#include <hip/hip_runtime.h>
#include <math.h>

#define N_DST   32768
#define N_EDGE  524288
#define LN_EPS  1e-5f

typedef __attribute__((ext_vector_type(8))) short short8b;   // 8 bf16 (4 VGPR)
typedef __attribute__((ext_vector_type(4))) float f32x4;

static __device__ __forceinline__ unsigned short f2bf(float f) {
    unsigned u = __float_as_uint(f);
    u += 0x7fff + ((u >> 16) & 1);          // round-to-nearest-even
    return (unsigned short)(u >> 16);
}
static __device__ __forceinline__ float bf2f(unsigned short s) {
    return __uint_as_float(((unsigned)s) << 16);
}
static __device__ __forceinline__ float dot4(float4 a, float4 b, float acc) {
    return fmaf(a.x, b.x, fmaf(a.y, b.y, fmaf(a.z, b.z, fmaf(a.w, b.w, acc))));
}

// ---------- prep: Wvp B-frag pack (padded K'=384), zq fold, wout transpose ----------
__global__ void k_prep(const float* __restrict__ wkv_w, const float* __restrict__ wq_w,
                       const float* __restrict__ wq_b, const float* __restrict__ time_b,
                       const float* __restrict__ wout_w,
                       unsigned short* __restrict__ Wvp, float* __restrict__ zq,
                       float* __restrict__ wout_t) {
    int idx = blockIdx.x * 256 + threadIdx.x;
    if (idx < 43008) {
        int jj = idx & 7, l = (idx >> 3) & 63, n = (idx >> 9) % 7, kc = idx / 3584;
        int c = n * 16 + (l & 15);
        int kp = kc * 32 + ((l >> 4) << 3) + jj;
        int region = kp >> 7, ridx = kp & 127;
        float v = (c < 100 && ridx < 100)
                  ? wkv_w[(size_t)(100 + c) * 300 + region * 100 + ridx] : 0.f;
        Wvp[idx] = f2bf(v);
    } else if (idx < 43108) {
        int o = idx - 43008;
        float acc = wq_b[o];
        for (int j = 0; j < 100; ++j)
            acc += cosf(time_b[j]) * wq_w[o * 200 + 100 + j];
        zq[o] = acc;
    } else if (idx < 63108) {
        int r = idx - 43108;                     // wout_t[i][o] = wout_w[o][i]
        wout_t[r] = wout_w[(size_t)(r % 100) * 200 + r / 100];
    }
}

// ---------- A[i][j] = sum_d wq_w[h*50+d][i] * wkv_w[h*50+d][j%300]  (j = h*300+kk) ----------
__global__ void k_precomp(const float* __restrict__ wq_w, const float* __restrict__ wkv_w,
                          const float* __restrict__ zq,
                          float* __restrict__ A, float* __restrict__ C) {
    int idx = blockIdx.x * 256 + threadIdx.x;
    if (idx < 60000) {
        int i = idx / 600, j = idx % 600;
        int h = j / 300, kk = j % 300;
        const float* __restrict__ wq = wq_w + (size_t)(h * 50) * 200 + i;
        const float* __restrict__ wk = wkv_w + (size_t)(h * 50) * 300 + kk;
        float acc = 0.f;
        #pragma unroll 10
        for (int d = 0; d < 50; ++d) acc = fmaf(wq[(size_t)d * 200], wk[(size_t)d * 300], acc);
        A[idx] = acc;
    } else if (idx < 60600) {
        int j = idx - 60000;
        int h = j / 300, kk = j % 300;
        float acc = 0.f;
        for (int d = 0; d < 50; ++d)
            acc = fmaf(zq[h * 50 + d], wkv_w[(size_t)(h * 50 + d) * 300 + kk], acc);
        C[j] = acc;
    }
}

// ---------- CSR offsets via binary search over sorted edge_dst ----------
__global__ void k_offsets(const int* __restrict__ dst, int* __restrict__ off) {
    int n = blockIdx.x * 256 + threadIdx.x;
    if (n > N_DST) return;
    int lo = 0, hi = N_EDGE;
    while (lo < hi) {
        int mid = (lo + hi) >> 1;
        if (dst[mid] < n) lo = mid + 1; else hi = mid;
    }
    off[n] = lo;
}

// ---------- QW = dst_h @ A + C : 32 nodes/block ----------
__global__ __launch_bounds__(256) void k_qw(const float* __restrict__ dst_h,
                                            const float* __restrict__ A,
                                            const float* __restrict__ C,
                                            float* __restrict__ QW) {
    __shared__ float Ds[32][100];
    int n0 = blockIdx.x * 32, t = threadIdx.x;
    for (int idx = t; idx < 3200; idx += 256)
        Ds[idx / 100][idx % 100] = dst_h[(size_t)n0 * 100 + idx];
    __syncthreads();
    for (int pass = 0; pass < 3; ++pass) {
        int c = pass * 256 + t;
        if (c >= 600) break;
        float cb = C[c];
        float acc[32];
        #pragma unroll
        for (int n = 0; n < 32; ++n) acc[n] = cb;
        for (int k = 0; k < 100; ++k) {
            float a = A[(size_t)k * 600 + c];
            #pragma unroll
            for (int n = 0; n < 32; ++n) acc[n] = fmaf(Ds[n][k], a, acc[n]);
        }
        #pragma unroll
        for (int n = 0; n < 32; ++n) QW[(size_t)(n0 + n) * 600 + c] = acc[n];
    }
}

// ---------- k_attn: fp32 logits, 4 lanes/edge, QW loads group-uniform (L1) ----------
__global__ __launch_bounds__(256, 4) void k_attn(
        const float* __restrict__ src_h, const float* __restrict__ efeat,
        const float* __restrict__ td,    const int* __restrict__ edge_dst,
        const float* __restrict__ time_w, const float* __restrict__ time_b,
        const float* __restrict__ QW,    float2* __restrict__ attn) {
    const int t = threadIdx.x;
    const int e = blockIdx.x * 64 + (t >> 2), s = t & 3;
    const int dst = edge_dst[e];
    const float tdv = td[e];
    const float* __restrict__ qwb = QW + (size_t)dst * 600;
    const float4* __restrict__ s4 = (const float4*)(src_h + (size_t)e * 100);
    const float4* __restrict__ f4 = (const float4*)(efeat + (size_t)e * 100);
    float p0 = 0.f, p1 = 0.f;
    #pragma unroll
    for (int j = 0; j < 19; ++j) {
        int q = s + 4 * j;                       // covers 0..74 across the 4 lanes
        if (q < 75) {
            float4 x;
            if (q < 25) {
                x = s4[q];
            } else if (q < 50) {
                x = f4[q - 25];
            } else {
                float4 tw = ((const float4*)time_w)[q - 50];
                float4 tb = ((const float4*)time_b)[q - 50];
                x.x = __cosf(fmaf(tdv, tw.x, tb.x));
                x.y = __cosf(fmaf(tdv, tw.y, tb.y));
                x.z = __cosf(fmaf(tdv, tw.z, tb.z));
                x.w = __cosf(fmaf(tdv, tw.w, tb.w));
            }
            float4 a0 = ((const float4*)qwb)[q];
            float4 a1 = ((const float4*)(qwb + 300))[q];
            p0 = dot4(x, a0, p0);
            p1 = dot4(x, a1, p1);
        }
    }
    p0 += __shfl_xor(p0, 1); p0 += __shfl_xor(p0, 2);
    p1 += __shfl_xor(p1, 1); p1 += __shfl_xor(p1, 2);
    if (s == 0) {
        attn[e] = make_float2(p0 > 0.f ? p0 : 0.2f * p0,
                              p1 > 0.f ? p1 : 0.2f * p1);
    }
}

// ---------- k_edge: PURE V-GEMM (no logits -> lean VGPR -> 3 waves/SIMD) ----------
__global__ __launch_bounds__(256, 1) void k_edge(
        const float* __restrict__ src_h, const float* __restrict__ efeat,
        const float* __restrict__ td,
        const float* __restrict__ time_w, const float* __restrict__ time_b,
        const unsigned short* __restrict__ Wvp, const float* __restrict__ wkv_b,
        unsigned short* __restrict__ Vb) {
    __shared__ alignas(16) unsigned short Wlds[21504];   // 42 KiB: 6 kc x 7 frags x 64 x 8
    const int t = threadIdx.x, lane = t & 63;
    const int g = blockIdx.x * 4 + (t >> 6);             // this wave: group g (16 edges)
    const int col = lane & 15, slice = lane >> 4;
    const int r0 = g * 16 + col;
    const float td0 = td[r0];
    const float4 z4 = make_float4(0.f, 0.f, 0.f, 0.f);

    // ---- Phase A: issue ALL src/efeat staging loads ----
    float4 s[16];
    #pragma unroll
    for (int kc = 0; kc < 8; ++kc) {
        const float* __restrict__ base = (kc < 4) ? src_h : efeat;
        const int idx0 = (kc & 3) * 32 + slice * 8;
        const float* b0 = base + (size_t)r0 * 100 + idx0;
        s[kc * 2]     = (idx0 <= 96) ? *(const float4*)b0       : z4;
        s[kc * 2 + 1] = (idx0 <= 88) ? *(const float4*)(b0 + 4) : z4;
    }
    // ---- Phase B: time features (VALU; overlaps staging) ----
    short8b af[12];
    #pragma unroll
    for (int kc = 8; kc < 12; ++kc) {
        const int idx0 = (kc & 3) * 32 + slice * 8;
        float4 xa = z4, xb = z4;
        if (idx0 <= 96) {
            float4 tw = *(const float4*)(time_w + idx0);
            float4 tb = *(const float4*)(time_b + idx0);
            xa.x = __cosf(fmaf(td0, tw.x, tb.x)); xa.y = __cosf(fmaf(td0, tw.y, tb.y));
            xa.z = __cosf(fmaf(td0, tw.z, tb.z)); xa.w = __cosf(fmaf(td0, tw.w, tb.w));
            if (idx0 <= 88) {
                float4 tw2 = *(const float4*)(time_w + idx0 + 4);
                float4 tb2 = *(const float4*)(time_b + idx0 + 4);
                xb.x = __cosf(fmaf(td0, tw2.x, tb2.x)); xb.y = __cosf(fmaf(td0, tw2.y, tb2.y));
                xb.z = __cosf(fmaf(td0, tw2.z, tb2.z)); xb.w = __cosf(fmaf(td0, tw2.w, tb2.w));
            }
        }
        short8b a;
        a[0] = (short)f2bf(xa.x); a[1] = (short)f2bf(xa.y);
        a[2] = (short)f2bf(xa.z); a[3] = (short)f2bf(xa.w);
        a[4] = (short)f2bf(xb.x); a[5] = (short)f2bf(xb.y);
        a[6] = (short)f2bf(xb.z); a[7] = (short)f2bf(xb.w);
        af[kc] = a;
    }
    // ---- Phase C: pack src/efeat A-frags ----
    #pragma unroll
    for (int kc = 0; kc < 8; ++kc) {
        float4 xa = s[kc * 2], xb = s[kc * 2 + 1];
        short8b a;
        a[0] = (short)f2bf(xa.x); a[1] = (short)f2bf(xa.y);
        a[2] = (short)f2bf(xa.z); a[3] = (short)f2bf(xa.w);
        a[4] = (short)f2bf(xb.x); a[5] = (short)f2bf(xb.y);
        a[6] = (short)f2bf(xb.z); a[7] = (short)f2bf(xb.w);
        af[kc] = a;
    }
    // ---- accumulators ----
    f32x4 acc0[7];
    #pragma unroll
    for (int n = 0; n < 7; ++n) {
        int cl = n * 16 + col;
        float b = (cl < 100) ? wkv_b[100 + cl] : 0.f;
        acc0[n] = (f32x4){b, b, b, b};
    }
    // ---- two halves: stage 6-kc slab of Wvp into LDS, then MFMA ----
    #pragma unroll
    for (int half = 0; half < 2; ++half) {
        {
            const float4* __restrict__ wsrc = (const float4*)Wvp + half * 2688;
            float4* __restrict__ wdst = (float4*)Wlds;
            #pragma unroll
            for (int i = 0; i < 10; ++i)
                wdst[i * 256 + t] = wsrc[i * 256 + t];
            if (t < 128) wdst[2560 + t] = wsrc[2560 + t];
        }
        __syncthreads();
        #pragma unroll
        for (int kl = 0; kl < 6; ++kl) {
            const int kc = half * 6 + kl;
            #pragma unroll
            for (int n = 0; n < 7; ++n) {
                short8b w = *(const short8b*)(&Wlds[(size_t)((kl * 7 + n) * 64 + lane) * 8]);
                acc0[n] = __builtin_amdgcn_mfma_f32_16x16x32_bf16(af[kc], w, acc0[n], 0, 0, 0);
            }
        }
        __syncthreads();
    }
    // V writeout (bf16, row-major): C/D layout col=lane&15, row=(lane>>4)*4+r
    const int re0 = g * 16 + (slice << 2);
    #pragma unroll
    for (int n = 0; n < 7; ++n) {
        int cl = n * 16 + col;
        if (cl < 100) {
            #pragma unroll
            for (int r = 0; r < 4; ++r)
                Vb[(size_t)(re0 + r) * 100 + cl] = f2bf(acc0[n][r]);
        }
    }
}

// ---------- segment softmax + weighted V reduce: one wave/node, 4-way unrolled chain ----------
__global__ __launch_bounds__(256) void k_soft(const float2* __restrict__ attn,
                                              const unsigned short* __restrict__ V,
                                              const int* __restrict__ off,
                                              float* __restrict__ agg) {
    const int lane = threadIdx.x & 63;
    const int n = blockIdx.x * 4 + (threadIdx.x >> 6);
    const int r0 = off[n], cnt = off[n + 1] - r0;
    float* __restrict__ aout = agg + (size_t)n * 100;
    if (cnt <= 0) {
        aout[lane] = 0.f;
        if (lane < 36) aout[64 + lane] = 0.f;
        return;
    }
    float m0 = -1e30f, m1 = -1e30f;
    for (int i = lane; i < cnt; i += 64) {
        float2 a = attn[r0 + i];
        m0 = fmaxf(m0, a.x); m1 = fmaxf(m1, a.y);
    }
    #pragma unroll
    for (int s = 1; s < 64; s <<= 1) {
        m0 = fmaxf(m0, __shfl_xor(m0, s));
        m1 = fmaxf(m1, __shfl_xor(m1, s));
    }
    float s0 = 0.f, s1 = 0.f;
    for (int i = lane; i < cnt; i += 64) {
        float2 a = attn[r0 + i];
        s0 += __expf(a.x - m0); s1 += __expf(a.y - m1);
    }
    #pragma unroll
    for (int s = 1; s < 64; s <<= 1) { s0 += __shfl_xor(s0, s); s1 += __shfl_xor(s1, s); }
    const float inv0 = 1.f / s0, inv1 = 1.f / s1;

    float aa0 = 0.f, aa1 = 0.f, aa2 = 0.f, aa3 = 0.f;
    float ab0 = 0.f, ab1 = 0.f, ab2 = 0.f, ab3 = 0.f;
    for (int base = 0; base < cnt; base += 64) {
        int i = base + lane;
        float e0 = 0.f, e1 = 0.f;
        if (i < cnt) {
            float2 a = attn[r0 + i];
            e0 = __expf(a.x - m0) * inv0;
            e1 = __expf(a.y - m1) * inv1;
        }
        int lim = min(64, cnt - base);
        const unsigned short* __restrict__ vrow = V + (size_t)(r0 + base) * 100;
        int j = 0;
        for (; j + 4 <= lim; j += 4) {
            float q00 = __shfl(e0, j),     q10 = __shfl(e1, j);
            float q01 = __shfl(e0, j + 1), q11 = __shfl(e1, j + 1);
            float q02 = __shfl(e0, j + 2), q12 = __shfl(e1, j + 2);
            float q03 = __shfl(e0, j + 3), q13 = __shfl(e1, j + 3);
            const unsigned short* w0 = vrow + (size_t)j * 100;
            float pa0 = (lane < 50) ? q00 : q10;
            float pa1 = (lane < 50) ? q01 : q11;
            float pa2 = (lane < 50) ? q02 : q12;
            float pa3 = (lane < 50) ? q03 : q13;
            aa0 = fmaf(pa0, bf2f(w0[lane]),       aa0);
            aa1 = fmaf(pa1, bf2f(w0[100 + lane]), aa1);
            aa2 = fmaf(pa2, bf2f(w0[200 + lane]), aa2);
            aa3 = fmaf(pa3, bf2f(w0[300 + lane]), aa3);
            if (lane < 36) {
                ab0 = fmaf(q10, bf2f(w0[64 + lane]),  ab0);
                ab1 = fmaf(q11, bf2f(w0[164 + lane]), ab1);
                ab2 = fmaf(q12, bf2f(w0[264 + lane]), ab2);
                ab3 = fmaf(q13, bf2f(w0[364 + lane]), ab3);
            }
        }
        for (; j < lim; ++j) {
            float q0 = __shfl(e0, j), q1 = __shfl(e1, j);
            const unsigned short* w0 = vrow + (size_t)j * 100;
            float pa = (lane < 50) ? q0 : q1;
            aa0 = fmaf(pa, bf2f(w0[lane]), aa0);
            if (lane < 36) ab0 = fmaf(q1, bf2f(w0[64 + lane]), ab0);
        }
    }
    aout[lane] = (aa0 + aa1) + (aa2 + aa3);
    if (lane < 36) aout[64 + lane] = (ab0 + ab1) + (ab2 + ab3);
}

// ---------- out proj + relu + layernorm: 8 nodes/block, coalesced wout_t ----------
__global__ __launch_bounds__(128) void k_out(const float* __restrict__ agg,
                                             const float* __restrict__ dst_h,
                                             const float* __restrict__ wout_t,
                                             const float* __restrict__ wout_b,
                                             const float* __restrict__ ln_g,
                                             const float* __restrict__ ln_b,
                                             float* __restrict__ out) {
    __shared__ float Fs[8][200];
    __shared__ float red[8][128];
    const int n0 = blockIdx.x * 8, t = threadIdx.x;
    for (int idx = t; idx < 1600; idx += 128) {
        int n = idx / 200, i = idx % 200;
        Fs[n][i] = (i < 100) ? agg[(size_t)(n0 + n) * 100 + i]
                             : dst_h[(size_t)(n0 + n) * 100 + (i - 100)];
    }
    __syncthreads();
    float v[8] = {0.f, 0.f, 0.f, 0.f, 0.f, 0.f, 0.f, 0.f};
    if (t < 100) {
        float b = wout_b[t];
        #pragma unroll
        for (int n = 0; n < 8; ++n) v[n] = b;
        for (int i = 0; i < 200; ++i) {
            float w = wout_t[i * 100 + t];
            #pragma unroll
            for (int n = 0; n < 8; ++n) v[n] = fmaf(Fs[n][i], w, v[n]);
        }
        #pragma unroll
        for (int n = 0; n < 8; ++n) v[n] = fmaxf(v[n], 0.f);
    }
    #pragma unroll
    for (int n = 0; n < 8; ++n) red[n][t] = (t < 100) ? v[n] : 0.f;
    __syncthreads();
    for (int s = 64; s > 0; s >>= 1) {
        if (t < s) {
            #pragma unroll
            for (int n = 0; n < 8; ++n) red[n][t] += red[n][t + s];
        }
        __syncthreads();
    }
    float mu[8];
    #pragma unroll
    for (int n = 0; n < 8; ++n) mu[n] = red[n][0] * 0.01f;
    __syncthreads();
    #pragma unroll
    for (int n = 0; n < 8; ++n) {
        float dv = (t < 100) ? (v[n] - mu[n]) : 0.f;
        red[n][t] = dv * dv;
    }
    __syncthreads();
    for (int s = 64; s > 0; s >>= 1) {
        if (t < s) {
            #pragma unroll
            for (int n = 0; n < 8; ++n) red[n][t] += red[n][t + s];
        }
        __syncthreads();
    }
    if (t < 100) {
        #pragma unroll
        for (int n = 0; n < 8; ++n) {
            float var = red[n][0] * 0.01f;
            out[(size_t)(n0 + n) * 100 + t] =
                (v[n] - mu[n]) * rsqrtf(var + LN_EPS) * ln_g[t] + ln_b[t];
        }
    }
}

extern "C" void kernel_launch(void* const* d_in, const int* in_sizes, int n_in,
                              void* d_out, int out_size, void* d_ws, size_t ws_size,
                              hipStream_t stream) {
    const float* dst_h   = (const float*)d_in[0];
    const float* src_h   = (const float*)d_in[1];
    const float* efeat   = (const float*)d_in[2];
    const float* td      = (const float*)d_in[3];
    const int*   edst    = (const int*)  d_in[4];
    const float* time_w  = (const float*)d_in[5];
    const float* time_b  = (const float*)d_in[6];
    const float* wq_w    = (const float*)d_in[7];
    const float* wq_b    = (const float*)d_in[8];
    const float* wkv_w   = (const float*)d_in[9];
    const float* wkv_b   = (const float*)d_in[10];
    const float* wout_w  = (const float*)d_in[11];
    const float* wout_b  = (const float*)d_in[12];
    const float* ln_g    = (const float*)d_in[13];
    const float* ln_b    = (const float*)d_in[14];
    float* out = (float*)d_out;

    char* ws = (char*)d_ws;
    size_t off = 0;
    auto carve = [&](size_t bytes) { char* p = ws + off; off = (off + bytes + 255) & ~(size_t)255; return p; };
    float*          QW    = (float*)carve((size_t)N_DST * 600 * 4);
    float2*         attn  = (float2*)carve((size_t)N_EDGE * 2 * 4);
    unsigned short* Vb    = (unsigned short*)carve((size_t)N_EDGE * 100 * 2);
    float*          agg   = (float*)carve((size_t)N_DST * 100 * 4);
    unsigned short* Wvp   = (unsigned short*)carve(43008 * 2);
    float*          zq    = (float*)carve(100 * 4);
    float*          A     = (float*)carve(60000 * 4);
    float*          C     = (float*)carve(600 * 4);
    float*          woutT = (float*)carve(20000 * 4);
    int*            offs  = (int*)carve((size_t)(N_DST + 1) * 4);

    k_prep<<<(63108 + 255) / 256, 256, 0, stream>>>(wkv_w, wq_w, wq_b, time_b, wout_w,
                                                    Wvp, zq, woutT);
    k_precomp<<<(60600 + 255) / 256, 256, 0, stream>>>(wq_w, wkv_w, zq, A, C);
    k_offsets<<<(N_DST + 1 + 255) / 256, 256, 0, stream>>>(edst, offs);
    k_qw<<<N_DST / 32, 256, 0, stream>>>(dst_h, A, C, QW);
    k_attn<<<N_EDGE / 64, 256, 0, stream>>>(src_h, efeat, td, edst, time_w, time_b,
                                            QW, attn);
    k_edge<<<N_EDGE / 64, 256, 0, stream>>>(src_h, efeat, td, time_w, time_b,
                                            Wvp, wkv_b, Vb);
    k_soft<<<N_DST / 4, 256, 0, stream>>>(attn, Vb, offs, agg);
    k_out<<<N_DST / 8, 128, 0, stream>>>(agg, dst_h, woutT, wout_b, ln_g, ln_b, out);
}

// Round 14
// 466.089 us; speedup vs baseline: 1.4608x; 1.4608x over previous
//
#include <hip/hip_runtime.h>
#include <math.h>

#define N_DST   32768
#define N_EDGE  524288
#define LN_EPS  1e-5f

typedef __attribute__((ext_vector_type(8))) short short8b;   // 8 bf16 (4 VGPR)
typedef __attribute__((ext_vector_type(4))) float f32x4;

static __device__ __forceinline__ unsigned short f2bf(float f) {
    unsigned u = __float_as_uint(f);
    u += 0x7fff + ((u >> 16) & 1);          // round-to-nearest-even
    return (unsigned short)(u >> 16);
}
static __device__ __forceinline__ float bf2f(unsigned short s) {
    return __uint_as_float(((unsigned)s) << 16);
}

// ---------- prep: K+V weights -> MFMA B-frag order (padded K'=384), zq, wout^T ----------
// Wvp[part][kc][n][l][jj], part 0=K rows 0..99 of wkv_w, part 1=V rows 100..199.
__global__ void k_prep(const float* __restrict__ wkv_w, const float* __restrict__ wq_w,
                       const float* __restrict__ wq_b, const float* __restrict__ time_b,
                       const float* __restrict__ wout_w,
                       unsigned short* __restrict__ Wvp, float* __restrict__ zq,
                       float* __restrict__ wout_t) {
    int idx = blockIdx.x * 256 + threadIdx.x;
    if (idx < 86016) {
        int part = idx / 43008, r2 = idx % 43008;
        int jj = r2 & 7, l = (r2 >> 3) & 63, n = (r2 >> 9) % 7, kc = r2 / 3584;
        int c = n * 16 + (l & 15);
        int kp = kc * 32 + ((l >> 4) << 3) + jj;
        int region = kp >> 7, ridx = kp & 127;
        float v = (c < 100 && ridx < 100)
                  ? wkv_w[(size_t)(part * 100 + c) * 300 + region * 100 + ridx] : 0.f;
        Wvp[idx] = f2bf(v);
    } else if (idx < 86116) {
        int o = idx - 86016;
        float acc = wq_b[o];
        for (int j = 0; j < 100; ++j)
            acc += cosf(time_b[j]) * wq_w[o * 200 + 100 + j];
        zq[o] = acc;
    } else if (idx < 106116) {
        int r = idx - 86116;                    // wout_t[i][o] = wout_w[o][i]
        wout_t[r] = wout_w[(size_t)(r % 100) * 200 + r / 100];
    }
}

// ---------- CSR offsets via binary search over sorted edge_dst ----------
__global__ void k_offsets(const int* __restrict__ dst, int* __restrict__ off) {
    int n = blockIdx.x * 256 + threadIdx.x;
    if (n > N_DST) return;
    int lo = 0, hi = N_EDGE;
    while (lo < hi) {
        int mid = (lo + hi) >> 1;
        if (dst[mid] < n) lo = mid + 1; else hi = mid;
    }
    off[n] = lo;
}

// ---------- Q = dst_h @ wq_w[:, :100].T + zq  (zq folds wq_b + zero-time term) ----------
__global__ __launch_bounds__(128) void k_q(const float* __restrict__ dst_h,
                                           const float* __restrict__ wq_w,
                                           const float* __restrict__ zq,
                                           float* __restrict__ Q) {
    int n = blockIdx.x, t = threadIdx.x;
    __shared__ float dl[100];
    if (t < 100) dl[t] = dst_h[(size_t)n * 100 + t];
    __syncthreads();
    if (t < 100) {
        float acc = zq[t];
        const float* __restrict__ wr = wq_w + t * 200;
        #pragma unroll 4
        for (int i = 0; i < 100; ++i) acc = fmaf(dl[i], wr[i], acc);
        Q[(size_t)n * 100 + t] = acc;
    }
}

// ---------- k_edge: dual MFMA pass. K stays in ACCUMULATORS -> logits in epilogue ----------
// Part 0 (K): 84 MFMA, then per-lane Q[dst]*K partial dots + 16-lane reduce -> attn.
// Part 1 (V): 84 MFMA -> Vb. af[12] A-frags shared. Wlds re-staged per 6-kc slab.
__global__ __launch_bounds__(256, 1) void k_edge(
        const float* __restrict__ src_h, const float* __restrict__ efeat,
        const float* __restrict__ td,    const int* __restrict__ edge_dst,
        const float* __restrict__ time_w, const float* __restrict__ time_b,
        const unsigned short* __restrict__ Wvp, const float* __restrict__ wkv_b,
        const float* __restrict__ Q,
        unsigned short* __restrict__ Vb, float2* __restrict__ attn) {
    __shared__ alignas(16) unsigned short Wlds[21504];   // 42 KiB slab: 6 kc x 7 x 64 x 8
    const int t = threadIdx.x, lane = t & 63;
    const int g = blockIdx.x * 4 + (t >> 6);             // wave: group g (16 edges)
    const int col = lane & 15, slice = lane >> 4;
    const int r0 = g * 16 + col;
    const float td0 = td[r0];
    const float4 z4 = make_float4(0.f, 0.f, 0.f, 0.f);

    // ---- Phase A: issue ALL src/efeat staging loads ----
    float4 s[16];
    #pragma unroll
    for (int kc = 0; kc < 8; ++kc) {
        const float* __restrict__ base = (kc < 4) ? src_h : efeat;
        const int idx0 = (kc & 3) * 32 + slice * 8;
        const float* b0 = base + (size_t)r0 * 100 + idx0;
        s[kc * 2]     = (idx0 <= 96) ? *(const float4*)b0       : z4;
        s[kc * 2 + 1] = (idx0 <= 88) ? *(const float4*)(b0 + 4) : z4;
    }
    // ---- Phase B: time features (VALU; overlaps staging) ----
    short8b af[12];
    #pragma unroll
    for (int kc = 8; kc < 12; ++kc) {
        const int idx0 = (kc & 3) * 32 + slice * 8;
        float4 xa = z4, xb = z4;
        if (idx0 <= 96) {
            float4 tw = *(const float4*)(time_w + idx0);
            float4 tb = *(const float4*)(time_b + idx0);
            xa.x = __cosf(fmaf(td0, tw.x, tb.x)); xa.y = __cosf(fmaf(td0, tw.y, tb.y));
            xa.z = __cosf(fmaf(td0, tw.z, tb.z)); xa.w = __cosf(fmaf(td0, tw.w, tb.w));
            if (idx0 <= 88) {
                float4 tw2 = *(const float4*)(time_w + idx0 + 4);
                float4 tb2 = *(const float4*)(time_b + idx0 + 4);
                xb.x = __cosf(fmaf(td0, tw2.x, tb2.x)); xb.y = __cosf(fmaf(td0, tw2.y, tb2.y));
                xb.z = __cosf(fmaf(td0, tw2.z, tb2.z)); xb.w = __cosf(fmaf(td0, tw2.w, tb2.w));
            }
        }
        short8b a;
        a[0] = (short)f2bf(xa.x); a[1] = (short)f2bf(xa.y);
        a[2] = (short)f2bf(xa.z); a[3] = (short)f2bf(xa.w);
        a[4] = (short)f2bf(xb.x); a[5] = (short)f2bf(xb.y);
        a[6] = (short)f2bf(xb.z); a[7] = (short)f2bf(xb.w);
        af[kc] = a;
    }
    // ---- Phase C: pack src/efeat A-frags ----
    #pragma unroll
    for (int kc = 0; kc < 8; ++kc) {
        float4 xa = s[kc * 2], xb = s[kc * 2 + 1];
        short8b a;
        a[0] = (short)f2bf(xa.x); a[1] = (short)f2bf(xa.y);
        a[2] = (short)f2bf(xa.z); a[3] = (short)f2bf(xa.w);
        a[4] = (short)f2bf(xb.x); a[5] = (short)f2bf(xb.y);
        a[6] = (short)f2bf(xb.z); a[7] = (short)f2bf(xb.w);
        af[kc] = a;
    }

    f32x4 acc[7];
    const int re0 = g * 16 + (slice << 2);

    // ================= PART 0: K (logits; K never leaves registers) =================
    #pragma unroll
    for (int n = 0; n < 7; ++n) {
        int cl = n * 16 + col;
        float b = (cl < 100) ? wkv_b[cl] : 0.f;         // K bias INCLUDED (exact)
        acc[n] = (f32x4){b, b, b, b};
    }
    #pragma unroll
    for (int half = 0; half < 2; ++half) {
        {
            const float4* __restrict__ wsrc = (const float4*)Wvp + half * 2688;
            float4* __restrict__ wdst = (float4*)Wlds;
            #pragma unroll
            for (int i = 0; i < 10; ++i) wdst[i * 256 + t] = wsrc[i * 256 + t];
            if (t < 128) wdst[2560 + t] = wsrc[2560 + t];
        }
        __syncthreads();
        #pragma unroll
        for (int kl = 0; kl < 6; ++kl) {
            const int kc = half * 6 + kl;
            #pragma unroll
            for (int n = 0; n < 7; ++n) {
                short8b w = *(const short8b*)(&Wlds[(size_t)((kl * 7 + n) * 64 + lane) * 8]);
                acc[n] = __builtin_amdgcn_mfma_f32_16x16x32_bf16(af[kc], w, acc[n], 0, 0, 0);
            }
        }
        __syncthreads();
    }
    // K epilogue: logit[e][h] = sum_cl Q[dst(e)][cl] * K[e][cl], h = cl/50
    {
        int dstr[4];
        #pragma unroll
        for (int r = 0; r < 4; ++r) dstr[r] = edge_dst[re0 + r];
        float p0[4] = {0.f, 0.f, 0.f, 0.f}, p1[4] = {0.f, 0.f, 0.f, 0.f};
        #pragma unroll
        for (int n = 0; n < 7; ++n) {
            int cl = n * 16 + col;
            if (cl < 100) {
                bool h0 = (cl < 50);
                #pragma unroll
                for (int r = 0; r < 4; ++r) {
                    float q = Q[(size_t)dstr[r] * 100 + cl];
                    if (h0) p0[r] = fmaf(q, acc[n][r], p0[r]);
                    else    p1[r] = fmaf(q, acc[n][r], p1[r]);
                }
            }
        }
        #pragma unroll
        for (int r = 0; r < 4; ++r) {
            #pragma unroll
            for (int sh = 1; sh < 16; sh <<= 1) {       // reduce within 16-lane col group
                p0[r] += __shfl_xor(p0[r], sh);
                p1[r] += __shfl_xor(p1[r], sh);
            }
        }
        if (col == 0) {
            #pragma unroll
            for (int r = 0; r < 4; ++r) {
                float l0 = p0[r] > 0.f ? p0[r] : 0.2f * p0[r];
                float l1 = p1[r] > 0.f ? p1[r] : 0.2f * p1[r];
                attn[re0 + r] = make_float2(l0, l1);
            }
        }
    }

    // ================= PART 1: V =================
    #pragma unroll
    for (int n = 0; n < 7; ++n) {
        int cl = n * 16 + col;
        float b = (cl < 100) ? wkv_b[100 + cl] : 0.f;
        acc[n] = (f32x4){b, b, b, b};
    }
    #pragma unroll
    for (int half = 0; half < 2; ++half) {
        {
            const float4* __restrict__ wsrc = (const float4*)Wvp + (2 + half) * 2688;
            float4* __restrict__ wdst = (float4*)Wlds;
            #pragma unroll
            for (int i = 0; i < 10; ++i) wdst[i * 256 + t] = wsrc[i * 256 + t];
            if (t < 128) wdst[2560 + t] = wsrc[2560 + t];
        }
        __syncthreads();
        #pragma unroll
        for (int kl = 0; kl < 6; ++kl) {
            const int kc = half * 6 + kl;
            #pragma unroll
            for (int n = 0; n < 7; ++n) {
                short8b w = *(const short8b*)(&Wlds[(size_t)((kl * 7 + n) * 64 + lane) * 8]);
                acc[n] = __builtin_amdgcn_mfma_f32_16x16x32_bf16(af[kc], w, acc[n], 0, 0, 0);
            }
        }
        __syncthreads();
    }
    // V writeout (bf16, row-major): C/D layout col=lane&15, row=(lane>>4)*4+r
    #pragma unroll
    for (int n = 0; n < 7; ++n) {
        int cl = n * 16 + col;
        if (cl < 100) {
            #pragma unroll
            for (int r = 0; r < 4; ++r)
                Vb[(size_t)(re0 + r) * 100 + cl] = f2bf(acc[n][r]);
        }
    }
}

// ---------- segment softmax + weighted V reduce: one wave/node, 4-way unrolled chain ----------
__global__ __launch_bounds__(256) void k_soft(const float2* __restrict__ attn,
                                              const unsigned short* __restrict__ V,
                                              const int* __restrict__ off,
                                              float* __restrict__ agg) {
    const int lane = threadIdx.x & 63;
    const int n = blockIdx.x * 4 + (threadIdx.x >> 6);
    const int r0 = off[n], cnt = off[n + 1] - r0;
    float* __restrict__ aout = agg + (size_t)n * 100;
    if (cnt <= 0) {
        aout[lane] = 0.f;
        if (lane < 36) aout[64 + lane] = 0.f;
        return;
    }
    float m0 = -1e30f, m1 = -1e30f;
    for (int i = lane; i < cnt; i += 64) {
        float2 a = attn[r0 + i];
        m0 = fmaxf(m0, a.x); m1 = fmaxf(m1, a.y);
    }
    #pragma unroll
    for (int s = 1; s < 64; s <<= 1) {
        m0 = fmaxf(m0, __shfl_xor(m0, s));
        m1 = fmaxf(m1, __shfl_xor(m1, s));
    }
    float s0 = 0.f, s1 = 0.f;
    for (int i = lane; i < cnt; i += 64) {
        float2 a = attn[r0 + i];
        s0 += __expf(a.x - m0); s1 += __expf(a.y - m1);
    }
    #pragma unroll
    for (int s = 1; s < 64; s <<= 1) { s0 += __shfl_xor(s0, s); s1 += __shfl_xor(s1, s); }
    const float inv0 = 1.f / s0, inv1 = 1.f / s1;

    float aa0 = 0.f, aa1 = 0.f, aa2 = 0.f, aa3 = 0.f;
    float ab0 = 0.f, ab1 = 0.f, ab2 = 0.f, ab3 = 0.f;
    for (int base = 0; base < cnt; base += 64) {
        int i = base + lane;
        float e0 = 0.f, e1 = 0.f;
        if (i < cnt) {
            float2 a = attn[r0 + i];
            e0 = __expf(a.x - m0) * inv0;
            e1 = __expf(a.y - m1) * inv1;
        }
        int lim = min(64, cnt - base);
        const unsigned short* __restrict__ vrow = V + (size_t)(r0 + base) * 100;
        int j = 0;
        for (; j + 4 <= lim; j += 4) {
            float q00 = __shfl(e0, j),     q10 = __shfl(e1, j);
            float q01 = __shfl(e0, j + 1), q11 = __shfl(e1, j + 1);
            float q02 = __shfl(e0, j + 2), q12 = __shfl(e1, j + 2);
            float q03 = __shfl(e0, j + 3), q13 = __shfl(e1, j + 3);
            const unsigned short* w0 = vrow + (size_t)j * 100;
            float pa0 = (lane < 50) ? q00 : q10;
            float pa1 = (lane < 50) ? q01 : q11;
            float pa2 = (lane < 50) ? q02 : q12;
            float pa3 = (lane < 50) ? q03 : q13;
            aa0 = fmaf(pa0, bf2f(w0[lane]),       aa0);
            aa1 = fmaf(pa1, bf2f(w0[100 + lane]), aa1);
            aa2 = fmaf(pa2, bf2f(w0[200 + lane]), aa2);
            aa3 = fmaf(pa3, bf2f(w0[300 + lane]), aa3);
            if (lane < 36) {
                ab0 = fmaf(q10, bf2f(w0[64 + lane]),  ab0);
                ab1 = fmaf(q11, bf2f(w0[164 + lane]), ab1);
                ab2 = fmaf(q12, bf2f(w0[264 + lane]), ab2);
                ab3 = fmaf(q13, bf2f(w0[364 + lane]), ab3);
            }
        }
        for (; j < lim; ++j) {
            float q0 = __shfl(e0, j), q1 = __shfl(e1, j);
            const unsigned short* w0 = vrow + (size_t)j * 100;
            float pa = (lane < 50) ? q0 : q1;
            aa0 = fmaf(pa, bf2f(w0[lane]), aa0);
            if (lane < 36) ab0 = fmaf(q1, bf2f(w0[64 + lane]), ab0);
        }
    }
    aout[lane] = (aa0 + aa1) + (aa2 + aa3);
    if (lane < 36) aout[64 + lane] = (ab0 + ab1) + (ab2 + ab3);
}

// ---------- out proj + relu + layernorm: 8 nodes/block, coalesced wout_t ----------
__global__ __launch_bounds__(128) void k_out(const float* __restrict__ agg,
                                             const float* __restrict__ dst_h,
                                             const float* __restrict__ wout_t,
                                             const float* __restrict__ wout_b,
                                             const float* __restrict__ ln_g,
                                             const float* __restrict__ ln_b,
                                             float* __restrict__ out) {
    __shared__ float Fs[8][200];
    __shared__ float red[8][128];
    const int n0 = blockIdx.x * 8, t = threadIdx.x;
    for (int idx = t; idx < 1600; idx += 128) {
        int n = idx / 200, i = idx % 200;
        Fs[n][i] = (i < 100) ? agg[(size_t)(n0 + n) * 100 + i]
                             : dst_h[(size_t)(n0 + n) * 100 + (i - 100)];
    }
    __syncthreads();
    float v[8] = {0.f, 0.f, 0.f, 0.f, 0.f, 0.f, 0.f, 0.f};
    if (t < 100) {
        float b = wout_b[t];
        #pragma unroll
        for (int n = 0; n < 8; ++n) v[n] = b;
        for (int i = 0; i < 200; ++i) {
            float w = wout_t[i * 100 + t];
            #pragma unroll
            for (int n = 0; n < 8; ++n) v[n] = fmaf(Fs[n][i], w, v[n]);
        }
        #pragma unroll
        for (int n = 0; n < 8; ++n) v[n] = fmaxf(v[n], 0.f);
    }
    #pragma unroll
    for (int n = 0; n < 8; ++n) red[n][t] = (t < 100) ? v[n] : 0.f;
    __syncthreads();
    for (int s = 64; s > 0; s >>= 1) {
        if (t < s) {
            #pragma unroll
            for (int n = 0; n < 8; ++n) red[n][t] += red[n][t + s];
        }
        __syncthreads();
    }
    float mu[8];
    #pragma unroll
    for (int n = 0; n < 8; ++n) mu[n] = red[n][0] * 0.01f;
    __syncthreads();
    #pragma unroll
    for (int n = 0; n < 8; ++n) {
        float dv = (t < 100) ? (v[n] - mu[n]) : 0.f;
        red[n][t] = dv * dv;
    }
    __syncthreads();
    for (int s = 64; s > 0; s >>= 1) {
        if (t < s) {
            #pragma unroll
            for (int n = 0; n < 8; ++n) red[n][t] += red[n][t + s];
        }
        __syncthreads();
    }
    if (t < 100) {
        #pragma unroll
        for (int n = 0; n < 8; ++n) {
            float var = red[n][0] * 0.01f;
            out[(size_t)(n0 + n) * 100 + t] =
                (v[n] - mu[n]) * rsqrtf(var + LN_EPS) * ln_g[t] + ln_b[t];
        }
    }
}

extern "C" void kernel_launch(void* const* d_in, const int* in_sizes, int n_in,
                              void* d_out, int out_size, void* d_ws, size_t ws_size,
                              hipStream_t stream) {
    const float* dst_h   = (const float*)d_in[0];
    const float* src_h   = (const float*)d_in[1];
    const float* efeat   = (const float*)d_in[2];
    const float* td      = (const float*)d_in[3];
    const int*   edst    = (const int*)  d_in[4];
    const float* time_w  = (const float*)d_in[5];
    const float* time_b  = (const float*)d_in[6];
    const float* wq_w    = (const float*)d_in[7];
    const float* wq_b    = (const float*)d_in[8];
    const float* wkv_w   = (const float*)d_in[9];
    const float* wkv_b   = (const float*)d_in[10];
    const float* wout_w  = (const float*)d_in[11];
    const float* wout_b  = (const float*)d_in[12];
    const float* ln_g    = (const float*)d_in[13];
    const float* ln_b    = (const float*)d_in[14];
    float* out = (float*)d_out;

    char* ws = (char*)d_ws;
    size_t off = 0;
    auto carve = [&](size_t bytes) { char* p = ws + off; off = (off + bytes + 255) & ~(size_t)255; return p; };
    float*          Q     = (float*)carve((size_t)N_DST * 100 * 4);
    float2*         attn  = (float2*)carve((size_t)N_EDGE * 2 * 4);
    unsigned short* Vb    = (unsigned short*)carve((size_t)N_EDGE * 100 * 2);
    float*          agg   = (float*)carve((size_t)N_DST * 100 * 4);
    unsigned short* Wvp   = (unsigned short*)carve(86016 * 2);
    float*          zq    = (float*)carve(100 * 4);
    float*          woutT = (float*)carve(20000 * 4);
    int*            offs  = (int*)carve((size_t)(N_DST + 1) * 4);

    k_prep<<<(106116 + 255) / 256, 256, 0, stream>>>(wkv_w, wq_w, wq_b, time_b, wout_w,
                                                     Wvp, zq, woutT);
    k_offsets<<<(N_DST + 1 + 255) / 256, 256, 0, stream>>>(edst, offs);
    k_q<<<N_DST, 128, 0, stream>>>(dst_h, wq_w, zq, Q);
    k_edge<<<N_EDGE / 64, 256, 0, stream>>>(src_h, efeat, td, edst, time_w, time_b,
                                            Wvp, wkv_b, Q, Vb, attn);
    k_soft<<<N_DST / 4, 256, 0, stream>>>(attn, Vb, offs, agg);
    k_out<<<N_DST / 8, 128, 0, stream>>>(agg, dst_h, woutT, wout_b, ln_g, ln_b, out);
}

// Round 15
// 397.387 us; speedup vs baseline: 1.7134x; 1.1729x over previous
//
#include <hip/hip_runtime.h>
#include <math.h>

#define N_DST   32768
#define N_EDGE  524288
#define LN_EPS  1e-5f

typedef __attribute__((ext_vector_type(8))) short short8b;   // 8 bf16 (4 VGPR)
typedef __attribute__((ext_vector_type(4))) float f32x4;

static __device__ __forceinline__ unsigned short f2bf(float f) {
    unsigned u = __float_as_uint(f);
    u += 0x7fff + ((u >> 16) & 1);          // round-to-nearest-even
    return (unsigned short)(u >> 16);
}
static __device__ __forceinline__ float bf2f(unsigned short s) {
    return __uint_as_float(((unsigned)s) << 16);
}

// ---------- prep: K+V weights -> MFMA B-frag order (padded K'=384), zq, wout^T ----------
// Wvp[part][kc][n][l][jj], part 0=K rows 0..99 of wkv_w, part 1=V rows 100..199.
__global__ void k_prep(const float* __restrict__ wkv_w, const float* __restrict__ wq_w,
                       const float* __restrict__ wq_b, const float* __restrict__ time_b,
                       const float* __restrict__ wout_w,
                       unsigned short* __restrict__ Wvp, float* __restrict__ zq,
                       float* __restrict__ wout_t) {
    int idx = blockIdx.x * 256 + threadIdx.x;
    if (idx < 86016) {
        int part = idx / 43008, r2 = idx % 43008;
        int jj = r2 & 7, l = (r2 >> 3) & 63, n = (r2 >> 9) % 7, kc = r2 / 3584;
        int c = n * 16 + (l & 15);
        int kp = kc * 32 + ((l >> 4) << 3) + jj;
        int region = kp >> 7, ridx = kp & 127;
        float v = (c < 100 && ridx < 100)
                  ? wkv_w[(size_t)(part * 100 + c) * 300 + region * 100 + ridx] : 0.f;
        Wvp[idx] = f2bf(v);
    } else if (idx < 86116) {
        int o = idx - 86016;
        float acc = wq_b[o];
        for (int j = 0; j < 100; ++j)
            acc += cosf(time_b[j]) * wq_w[o * 200 + 100 + j];
        zq[o] = acc;
    } else if (idx < 106116) {
        int r = idx - 86116;                    // wout_t[i][o] = wout_w[o][i]
        wout_t[r] = wout_w[(size_t)(r % 100) * 200 + r / 100];
    }
}

// ---------- CSR offsets via binary search over sorted edge_dst ----------
__global__ void k_offsets(const int* __restrict__ dst, int* __restrict__ off) {
    int n = blockIdx.x * 256 + threadIdx.x;
    if (n > N_DST) return;
    int lo = 0, hi = N_EDGE;
    while (lo < hi) {
        int mid = (lo + hi) >> 1;
        if (dst[mid] < n) lo = mid + 1; else hi = mid;
    }
    off[n] = lo;
}

// ---------- Q = dst_h @ wq_w[:, :100].T + zq : 16 nodes/block (wq_w row reused 16x) ----------
__global__ __launch_bounds__(128) void k_q(const float* __restrict__ dst_h,
                                           const float* __restrict__ wq_w,
                                           const float* __restrict__ zq,
                                           float* __restrict__ Q) {
    __shared__ float Ds[16][100];
    int n0 = blockIdx.x * 16, t = threadIdx.x;
    for (int idx = t; idx < 1600; idx += 128)
        Ds[idx / 100][idx % 100] = dst_h[(size_t)n0 * 100 + idx];
    __syncthreads();
    if (t < 100) {
        float z = zq[t];
        float acc[16];
        #pragma unroll
        for (int n = 0; n < 16; ++n) acc[n] = z;
        const float* __restrict__ wr = wq_w + t * 200;
        for (int i = 0; i < 100; ++i) {
            float w = wr[i];
            #pragma unroll
            for (int n = 0; n < 16; ++n) acc[n] = fmaf(Ds[n][i], w, acc[n]);
        }
        #pragma unroll
        for (int n = 0; n < 16; ++n) Q[(size_t)(n0 + n) * 100 + t] = acc[n];
    }
}

// ---------- k_edge: dual MFMA pass, 21 KB LDS slabs (3 kc) for ~4 blocks/CU ----------
// Part 0 (K): 84 MFMA -> logits epilogue (K never leaves registers).
// Part 1 (V): 84 MFMA -> Vb. af[12] A-frags shared across parts.
__global__ __launch_bounds__(256, 1) void k_edge(
        const float* __restrict__ src_h, const float* __restrict__ efeat,
        const float* __restrict__ td,    const int* __restrict__ edge_dst,
        const float* __restrict__ time_w, const float* __restrict__ time_b,
        const unsigned short* __restrict__ Wvp, const float* __restrict__ wkv_b,
        const float* __restrict__ Q,
        unsigned short* __restrict__ Vb, float2* __restrict__ attn) {
    __shared__ alignas(16) unsigned short Wlds[10752];   // 21 KiB slab: 3 kc x 7 x 64 x 8
    const int t = threadIdx.x, lane = t & 63;
    const int g = blockIdx.x * 4 + (t >> 6);             // wave: group g (16 edges)
    const int col = lane & 15, slice = lane >> 4;
    const int r0 = g * 16 + col;
    const float td0 = td[r0];
    const float4 z4 = make_float4(0.f, 0.f, 0.f, 0.f);

    // ---- Phase A: issue ALL src/efeat staging loads ----
    float4 s[16];
    #pragma unroll
    for (int kc = 0; kc < 8; ++kc) {
        const float* __restrict__ base = (kc < 4) ? src_h : efeat;
        const int idx0 = (kc & 3) * 32 + slice * 8;
        const float* b0 = base + (size_t)r0 * 100 + idx0;
        s[kc * 2]     = (idx0 <= 96) ? *(const float4*)b0       : z4;
        s[kc * 2 + 1] = (idx0 <= 88) ? *(const float4*)(b0 + 4) : z4;
    }
    // ---- Phase B: time features (VALU; overlaps staging) ----
    short8b af[12];
    #pragma unroll
    for (int kc = 8; kc < 12; ++kc) {
        const int idx0 = (kc & 3) * 32 + slice * 8;
        float4 xa = z4, xb = z4;
        if (idx0 <= 96) {
            float4 tw = *(const float4*)(time_w + idx0);
            float4 tb = *(const float4*)(time_b + idx0);
            xa.x = __cosf(fmaf(td0, tw.x, tb.x)); xa.y = __cosf(fmaf(td0, tw.y, tb.y));
            xa.z = __cosf(fmaf(td0, tw.z, tb.z)); xa.w = __cosf(fmaf(td0, tw.w, tb.w));
            if (idx0 <= 88) {
                float4 tw2 = *(const float4*)(time_w + idx0 + 4);
                float4 tb2 = *(const float4*)(time_b + idx0 + 4);
                xb.x = __cosf(fmaf(td0, tw2.x, tb2.x)); xb.y = __cosf(fmaf(td0, tw2.y, tb2.y));
                xb.z = __cosf(fmaf(td0, tw2.z, tb2.z)); xb.w = __cosf(fmaf(td0, tw2.w, tb2.w));
            }
        }
        short8b a;
        a[0] = (short)f2bf(xa.x); a[1] = (short)f2bf(xa.y);
        a[2] = (short)f2bf(xa.z); a[3] = (short)f2bf(xa.w);
        a[4] = (short)f2bf(xb.x); a[5] = (short)f2bf(xb.y);
        a[6] = (short)f2bf(xb.z); a[7] = (short)f2bf(xb.w);
        af[kc] = a;
    }
    // ---- Phase C: pack src/efeat A-frags ----
    #pragma unroll
    for (int kc = 0; kc < 8; ++kc) {
        float4 xa = s[kc * 2], xb = s[kc * 2 + 1];
        short8b a;
        a[0] = (short)f2bf(xa.x); a[1] = (short)f2bf(xa.y);
        a[2] = (short)f2bf(xa.z); a[3] = (short)f2bf(xa.w);
        a[4] = (short)f2bf(xb.x); a[5] = (short)f2bf(xb.y);
        a[6] = (short)f2bf(xb.z); a[7] = (short)f2bf(xb.w);
        af[kc] = a;
    }

    f32x4 acc[7];
    const int re0 = g * 16 + (slice << 2);

    // ================= PART 0: K (logits; K never leaves registers) =================
    #pragma unroll
    for (int n = 0; n < 7; ++n) {
        int cl = n * 16 + col;
        float b = (cl < 100) ? wkv_b[cl] : 0.f;         // K bias INCLUDED (exact)
        acc[n] = (f32x4){b, b, b, b};
    }
    #pragma unroll
    for (int slab = 0; slab < 4; ++slab) {
        {   // stage 3-kc slab: 1344 float4 = 5*256 + 64
            const float4* __restrict__ wsrc = (const float4*)Wvp + slab * 1344;
            float4* __restrict__ wdst = (float4*)Wlds;
            #pragma unroll
            for (int i = 0; i < 5; ++i) wdst[i * 256 + t] = wsrc[i * 256 + t];
            if (t < 64) wdst[1280 + t] = wsrc[1280 + t];
        }
        __syncthreads();
        #pragma unroll
        for (int kl = 0; kl < 3; ++kl) {
            const int kc = slab * 3 + kl;
            #pragma unroll
            for (int n = 0; n < 7; ++n) {
                short8b w = *(const short8b*)(&Wlds[(size_t)((kl * 7 + n) * 64 + lane) * 8]);
                acc[n] = __builtin_amdgcn_mfma_f32_16x16x32_bf16(af[kc], w, acc[n], 0, 0, 0);
            }
        }
        __syncthreads();
    }
    // K epilogue: logit[e][h] = sum_cl Q[dst(e)][cl] * K[e][cl], h = cl/50
    {
        int dstr[4];
        #pragma unroll
        for (int r = 0; r < 4; ++r) dstr[r] = edge_dst[re0 + r];
        float p0[4] = {0.f, 0.f, 0.f, 0.f}, p1[4] = {0.f, 0.f, 0.f, 0.f};
        #pragma unroll
        for (int n = 0; n < 7; ++n) {
            int cl = n * 16 + col;
            if (cl < 100) {
                bool h0 = (cl < 50);
                #pragma unroll
                for (int r = 0; r < 4; ++r) {
                    float q = Q[(size_t)dstr[r] * 100 + cl];
                    if (h0) p0[r] = fmaf(q, acc[n][r], p0[r]);
                    else    p1[r] = fmaf(q, acc[n][r], p1[r]);
                }
            }
        }
        #pragma unroll
        for (int r = 0; r < 4; ++r) {
            #pragma unroll
            for (int sh = 1; sh < 16; sh <<= 1) {       // reduce within 16-lane col group
                p0[r] += __shfl_xor(p0[r], sh);
                p1[r] += __shfl_xor(p1[r], sh);
            }
        }
        if (col == 0) {
            #pragma unroll
            for (int r = 0; r < 4; ++r) {
                float l0 = p0[r] > 0.f ? p0[r] : 0.2f * p0[r];
                float l1 = p1[r] > 0.f ? p1[r] : 0.2f * p1[r];
                attn[re0 + r] = make_float2(l0, l1);
            }
        }
    }

    // ================= PART 1: V =================
    #pragma unroll
    for (int n = 0; n < 7; ++n) {
        int cl = n * 16 + col;
        float b = (cl < 100) ? wkv_b[100 + cl] : 0.f;
        acc[n] = (f32x4){b, b, b, b};
    }
    #pragma unroll
    for (int slab = 0; slab < 4; ++slab) {
        {
            const float4* __restrict__ wsrc = (const float4*)Wvp + (4 + slab) * 1344;
            float4* __restrict__ wdst = (float4*)Wlds;
            #pragma unroll
            for (int i = 0; i < 5; ++i) wdst[i * 256 + t] = wsrc[i * 256 + t];
            if (t < 64) wdst[1280 + t] = wsrc[1280 + t];
        }
        __syncthreads();
        #pragma unroll
        for (int kl = 0; kl < 3; ++kl) {
            const int kc = slab * 3 + kl;
            #pragma unroll
            for (int n = 0; n < 7; ++n) {
                short8b w = *(const short8b*)(&Wlds[(size_t)((kl * 7 + n) * 64 + lane) * 8]);
                acc[n] = __builtin_amdgcn_mfma_f32_16x16x32_bf16(af[kc], w, acc[n], 0, 0, 0);
            }
        }
        __syncthreads();
    }
    // V writeout (bf16, row-major): C/D layout col=lane&15, row=(lane>>4)*4+r
    #pragma unroll
    for (int n = 0; n < 7; ++n) {
        int cl = n * 16 + col;
        if (cl < 100) {
            #pragma unroll
            for (int r = 0; r < 4; ++r)
                Vb[(size_t)(re0 + r) * 100 + cl] = f2bf(acc[n][r]);
        }
    }
}

// ---------- segment softmax + weighted V reduce: one wave/node, 4-way unrolled chain ----------
__global__ __launch_bounds__(256) void k_soft(const float2* __restrict__ attn,
                                              const unsigned short* __restrict__ V,
                                              const int* __restrict__ off,
                                              float* __restrict__ agg) {
    const int lane = threadIdx.x & 63;
    const int n = blockIdx.x * 4 + (threadIdx.x >> 6);
    const int r0 = off[n], cnt = off[n + 1] - r0;
    float* __restrict__ aout = agg + (size_t)n * 100;
    if (cnt <= 0) {
        aout[lane] = 0.f;
        if (lane < 36) aout[64 + lane] = 0.f;
        return;
    }
    float m0 = -1e30f, m1 = -1e30f;
    for (int i = lane; i < cnt; i += 64) {
        float2 a = attn[r0 + i];
        m0 = fmaxf(m0, a.x); m1 = fmaxf(m1, a.y);
    }
    #pragma unroll
    for (int s = 1; s < 64; s <<= 1) {
        m0 = fmaxf(m0, __shfl_xor(m0, s));
        m1 = fmaxf(m1, __shfl_xor(m1, s));
    }
    float s0 = 0.f, s1 = 0.f;
    for (int i = lane; i < cnt; i += 64) {
        float2 a = attn[r0 + i];
        s0 += __expf(a.x - m0); s1 += __expf(a.y - m1);
    }
    #pragma unroll
    for (int s = 1; s < 64; s <<= 1) { s0 += __shfl_xor(s0, s); s1 += __shfl_xor(s1, s); }
    const float inv0 = 1.f / s0, inv1 = 1.f / s1;

    float aa0 = 0.f, aa1 = 0.f, aa2 = 0.f, aa3 = 0.f;
    float ab0 = 0.f, ab1 = 0.f, ab2 = 0.f, ab3 = 0.f;
    for (int base = 0; base < cnt; base += 64) {
        int i = base + lane;
        float e0 = 0.f, e1 = 0.f;
        if (i < cnt) {
            float2 a = attn[r0 + i];
            e0 = __expf(a.x - m0) * inv0;
            e1 = __expf(a.y - m1) * inv1;
        }
        int lim = min(64, cnt - base);
        const unsigned short* __restrict__ vrow = V + (size_t)(r0 + base) * 100;
        int j = 0;
        for (; j + 4 <= lim; j += 4) {
            float q00 = __shfl(e0, j),     q10 = __shfl(e1, j);
            float q01 = __shfl(e0, j + 1), q11 = __shfl(e1, j + 1);
            float q02 = __shfl(e0, j + 2), q12 = __shfl(e1, j + 2);
            float q03 = __shfl(e0, j + 3), q13 = __shfl(e1, j + 3);
            const unsigned short* w0 = vrow + (size_t)j * 100;
            float pa0 = (lane < 50) ? q00 : q10;
            float pa1 = (lane < 50) ? q01 : q11;
            float pa2 = (lane < 50) ? q02 : q12;
            float pa3 = (lane < 50) ? q03 : q13;
            aa0 = fmaf(pa0, bf2f(w0[lane]),       aa0);
            aa1 = fmaf(pa1, bf2f(w0[100 + lane]), aa1);
            aa2 = fmaf(pa2, bf2f(w0[200 + lane]), aa2);
            aa3 = fmaf(pa3, bf2f(w0[300 + lane]), aa3);
            if (lane < 36) {
                ab0 = fmaf(q10, bf2f(w0[64 + lane]),  ab0);
                ab1 = fmaf(q11, bf2f(w0[164 + lane]), ab1);
                ab2 = fmaf(q12, bf2f(w0[264 + lane]), ab2);
                ab3 = fmaf(q13, bf2f(w0[364 + lane]), ab3);
            }
        }
        for (; j < lim; ++j) {
            float q0 = __shfl(e0, j), q1 = __shfl(e1, j);
            const unsigned short* w0 = vrow + (size_t)j * 100;
            float pa = (lane < 50) ? q0 : q1;
            aa0 = fmaf(pa, bf2f(w0[lane]), aa0);
            if (lane < 36) ab0 = fmaf(q1, bf2f(w0[64 + lane]), ab0);
        }
    }
    aout[lane] = (aa0 + aa1) + (aa2 + aa3);
    if (lane < 36) aout[64 + lane] = (ab0 + ab1) + (ab2 + ab3);
}

// ---------- out proj + relu + layernorm: 8 nodes/block, coalesced wout_t ----------
__global__ __launch_bounds__(128) void k_out(const float* __restrict__ agg,
                                             const float* __restrict__ dst_h,
                                             const float* __restrict__ wout_t,
                                             const float* __restrict__ wout_b,
                                             const float* __restrict__ ln_g,
                                             const float* __restrict__ ln_b,
                                             float* __restrict__ out) {
    __shared__ float Fs[8][200];
    __shared__ float red[8][128];
    const int n0 = blockIdx.x * 8, t = threadIdx.x;
    for (int idx = t; idx < 1600; idx += 128) {
        int n = idx / 200, i = idx % 200;
        Fs[n][i] = (i < 100) ? agg[(size_t)(n0 + n) * 100 + i]
                             : dst_h[(size_t)(n0 + n) * 100 + (i - 100)];
    }
    __syncthreads();
    float v[8] = {0.f, 0.f, 0.f, 0.f, 0.f, 0.f, 0.f, 0.f};
    if (t < 100) {
        float b = wout_b[t];
        #pragma unroll
        for (int n = 0; n < 8; ++n) v[n] = b;
        for (int i = 0; i < 200; ++i) {
            float w = wout_t[i * 100 + t];
            #pragma unroll
            for (int n = 0; n < 8; ++n) v[n] = fmaf(Fs[n][i], w, v[n]);
        }
        #pragma unroll
        for (int n = 0; n < 8; ++n) v[n] = fmaxf(v[n], 0.f);
    }
    #pragma unroll
    for (int n = 0; n < 8; ++n) red[n][t] = (t < 100) ? v[n] : 0.f;
    __syncthreads();
    for (int s = 64; s > 0; s >>= 1) {
        if (t < s) {
            #pragma unroll
            for (int n = 0; n < 8; ++n) red[n][t] += red[n][t + s];
        }
        __syncthreads();
    }
    float mu[8];
    #pragma unroll
    for (int n = 0; n < 8; ++n) mu[n] = red[n][0] * 0.01f;
    __syncthreads();
    #pragma unroll
    for (int n = 0; n < 8; ++n) {
        float dv = (t < 100) ? (v[n] - mu[n]) : 0.f;
        red[n][t] = dv * dv;
    }
    __syncthreads();
    for (int s = 64; s > 0; s >>= 1) {
        if (t < s) {
            #pragma unroll
            for (int n = 0; n < 8; ++n) red[n][t] += red[n][t + s];
        }
        __syncthreads();
    }
    if (t < 100) {
        #pragma unroll
        for (int n = 0; n < 8; ++n) {
            float var = red[n][0] * 0.01f;
            out[(size_t)(n0 + n) * 100 + t] =
                (v[n] - mu[n]) * rsqrtf(var + LN_EPS) * ln_g[t] + ln_b[t];
        }
    }
}

extern "C" void kernel_launch(void* const* d_in, const int* in_sizes, int n_in,
                              void* d_out, int out_size, void* d_ws, size_t ws_size,
                              hipStream_t stream) {
    const float* dst_h   = (const float*)d_in[0];
    const float* src_h   = (const float*)d_in[1];
    const float* efeat   = (const float*)d_in[2];
    const float* td      = (const float*)d_in[3];
    const int*   edst    = (const int*)  d_in[4];
    const float* time_w  = (const float*)d_in[5];
    const float* time_b  = (const float*)d_in[6];
    const float* wq_w    = (const float*)d_in[7];
    const float* wq_b    = (const float*)d_in[8];
    const float* wkv_w   = (const float*)d_in[9];
    const float* wkv_b   = (const float*)d_in[10];
    const float* wout_w  = (const float*)d_in[11];
    const float* wout_b  = (const float*)d_in[12];
    const float* ln_g    = (const float*)d_in[13];
    const float* ln_b    = (const float*)d_in[14];
    float* out = (float*)d_out;

    char* ws = (char*)d_ws;
    size_t off = 0;
    auto carve = [&](size_t bytes) { char* p = ws + off; off = (off + bytes + 255) & ~(size_t)255; return p; };
    float*          Q     = (float*)carve((size_t)N_DST * 100 * 4);
    float2*         attn  = (float2*)carve((size_t)N_EDGE * 2 * 4);
    unsigned short* Vb    = (unsigned short*)carve((size_t)N_EDGE * 100 * 2);
    float*          agg   = (float*)carve((size_t)N_DST * 100 * 4);
    unsigned short* Wvp   = (unsigned short*)carve(86016 * 2);
    float*          zq    = (float*)carve(100 * 4);
    float*          woutT = (float*)carve(20000 * 4);
    int*            offs  = (int*)carve((size_t)(N_DST + 1) * 4);

    k_prep<<<(106116 + 255) / 256, 256, 0, stream>>>(wkv_w, wq_w, wq_b, time_b, wout_w,
                                                     Wvp, zq, woutT);
    k_offsets<<<(N_DST + 1 + 255) / 256, 256, 0, stream>>>(edst, offs);
    k_q<<<N_DST / 16, 128, 0, stream>>>(dst_h, wq_w, zq, Q);
    k_edge<<<N_EDGE / 64, 256, 0, stream>>>(src_h, efeat, td, edst, time_w, time_b,
                                            Wvp, wkv_b, Q, Vb, attn);
    k_soft<<<N_DST / 4, 256, 0, stream>>>(attn, Vb, offs, agg);
    k_out<<<N_DST / 8, 128, 0, stream>>>(agg, dst_h, woutT, wout_b, ln_g, ln_b, out);
}